// Round 4
// baseline (337.253 us; speedup 1.0000x reference)
//
#include <hip/hip_runtime.h>

// ConvNat: 2x NAT(31x31, 4 heads, dh=16) on 36x36x64 + dw-conv3x3 residual + linear.
// fp32. R4: split-K attention, 2 queries/lane (fits 128-VGPR / 4-waves-per-SIMD
// tier, no spills). grid = 324 tiles x 4 key-splits x 2 query-pairs.

namespace {

__device__ __forceinline__ int iclampi(int v, int lo, int hi) {
  return v < lo ? lo : (v > hi ? hi : v);
}

// out[n][t] = b[t] + sum_c x[n][c] * w[t][c]
// grid = 972 (4 pixels x 64-out chunk per block), block = 256
__global__ __launch_bounds__(256) void qkv_gemm(const float* __restrict__ xin,
                                                const float* __restrict__ w,
                                                const float* __restrict__ b,
                                                float* __restrict__ out) {
  __shared__ float xs[4][64];
  const int blk = blockIdx.x;
  const int oc = blk % 3;
  const int p0 = (blk / 3) * 4;
  const int tid = threadIdx.x;
  const int pl = tid >> 6, co = tid & 63;
  const int n = p0 + pl;
  xs[pl][co] = xin[n * 64 + co];
  __syncthreads();
  const int t = oc * 64 + co;
  const float4* w4 = (const float4*)(w + t * 64);
  float acc = b[t];
#pragma unroll
  for (int u = 0; u < 16; ++u) {
    float4 wv = w4[u];
    acc += xs[pl][u * 4 + 0] * wv.x + xs[pl][u * 4 + 1] * wv.y +
           xs[pl][u * 4 + 2] * wv.z + xs[pl][u * 4 + 3] * wv.w;
  }
  out[n * 192 + t] = acc;
}

// Split-K NAT partials, 2 queries per lane.
// grid = 324*4*2: bid -> tile = bid>>3, s = (bid>>1)&3, pr = bid&1.
// Block's queries: (i0+pr, j0) and (i0+pr, j0+1). Wave = head.
// Split s covers key rows [s*8, s*8+8) of the tile's <=32-row window union.
// Output record per (bid, head): 36 floats  [qq*17+d]=acc, [qq*17+16]=den.
__global__ __launch_bounds__(256, 4) void nat_attn_part(
    const float* __restrict__ qkv, const float* __restrict__ rpb,
    float* __restrict__ part) {
  __shared__ float lpart[4][16][35];  // [head][group][2q*17] stride 35 (odd)

  const int tid = threadIdx.x;
  const int h = tid >> 6;
  const int lane = tid & 63;
  const int bid = blockIdx.x;
  const int tile = bid >> 3;
  const int s = (bid >> 1) & 3;
  const int pr = bid & 1;
  const int i0 = (tile / 18) * 2;
  const int j0 = (tile % 18) * 2;

  // union window over the parent 2x2 tile (<= 32x32)
  const int r_lo = iclampi(i0 - 15, 0, 5);
  const int nRr = (iclampi(i0 - 14, 0, 5) + 30) - r_lo;  // 30 or 31
  const int c_lo = iclampi(j0 - 15, 0, 5);
  const int nCc = (iclampi(j0 - 14, 0, 5) + 30) - c_lo;

  const int iq = i0 + pr;                       // shared row of both queries
  const int riq = iclampi(iq - 15, 0, 5);
  int jq[2], cjq[2];
#pragma unroll
  for (int qq = 0; qq < 2; ++qq) {
    jq[qq] = j0 + qq;
    cjq[qq] = iclampi(jq[qq] - 15, 0, 5);
  }

  // queries, pre-scaled by dh^-0.5 = 0.25 (broadcast loads)
  float qv[2][16];
#pragma unroll
  for (int qq = 0; qq < 2; ++qq) {
    const float4* qp = (const float4*)(qkv + (iq * 36 + jq[qq]) * 192 + h * 16);
#pragma unroll
    for (int u = 0; u < 4; ++u) {
      float4 q4 = qp[u];
      qv[qq][u * 4 + 0] = q4.x * 0.25f;
      qv[qq][u * 4 + 1] = q4.y * 0.25f;
      qv[qq][u * 4 + 2] = q4.z * 0.25f;
      qv[qq][u * 4 + 3] = q4.w * 0.25f;
    }
  }

  float acc[2][16];
  float sden[2] = {0.f, 0.f};
#pragma unroll
  for (int qq = 0; qq < 2; ++qq)
#pragma unroll
    for (int d = 0; d < 16; ++d) acc[qq][d] = 0.f;

  const int lr = lane >> 5;
  const int lc = lane & 31;

#pragma unroll
  for (int rp = 0; rp < 4; ++rp) {
    const int krr = s * 8 + rp * 2 + lr;
    const int rA = r_lo + krr;
    const int cA = c_lo + lc;
    const bool act = (krr <= nRr) && (lc <= nCc);
    const int rL = rA > 35 ? 35 : rA;
    const int cL = cA > 35 ? 35 : cA;
    const float* kbase = qkv + (rL * 36 + cL) * 192 + 64 + h * 16;
    float vr_[16];
    float dot[2] = {0.f, 0.f};
#pragma unroll
    for (int u = 0; u < 4; ++u) {
      float4 k4 = ((const float4*)kbase)[u];
      dot[0] += qv[0][u * 4 + 0] * k4.x + qv[0][u * 4 + 1] * k4.y +
                qv[0][u * 4 + 2] * k4.z + qv[0][u * 4 + 3] * k4.w;
      dot[1] += qv[1][u * 4 + 0] * k4.x + qv[1][u * 4 + 1] * k4.y +
                qv[1][u * 4 + 2] * k4.z + qv[1][u * 4 + 3] * k4.w;
      float4 v4 = ((const float4*)(kbase + 64))[u];
      vr_[u * 4 + 0] = v4.x; vr_[u * 4 + 1] = v4.y;
      vr_[u * 4 + 2] = v4.z; vr_[u * 4 + 3] = v4.w;
    }
    const bool rowok = act && (rA >= riq) && (rA <= riq + 30);
    const int br = iclampi(rA - iq + 30, 0, 60);
#pragma unroll
    for (int qq = 0; qq < 2; ++qq) {
      const bool inw = rowok && (cA >= cjq[qq]) && (cA <= cjq[qq] + 30);
      const int bc = iclampi(cA - jq[qq] + 30, 0, 60);
      const float bias = rpb[h * 3721 + br * 61 + bc];
      // |logits| << 1 for this input distribution; clamp = overflow insurance
      const float lg = fminf(dot[qq] + bias, 25.f);
      const float p = inw ? __expf(lg) : 0.f;
      sden[qq] += p;
#pragma unroll
      for (int d = 0; d < 16; ++d) acc[qq][d] += p * vr_[d];
    }
  }

  // 2-step butterfly -> 16 groups of 4 lanes
#pragma unroll
  for (int qq = 0; qq < 2; ++qq) {
#pragma unroll
    for (int d = 0; d < 16; ++d) {
      acc[qq][d] += __shfl_xor(acc[qq][d], 1);
      acc[qq][d] += __shfl_xor(acc[qq][d], 2);
    }
    sden[qq] += __shfl_xor(sden[qq], 1);
    sden[qq] += __shfl_xor(sden[qq], 2);
  }

  if ((lane & 3) == 0) {
    const int row = lane >> 2;
#pragma unroll
    for (int qq = 0; qq < 2; ++qq) {
#pragma unroll
      for (int d = 0; d < 16; ++d) lpart[h][row][qq * 17 + d] = acc[qq][d];
      lpart[h][row][qq * 17 + 16] = sden[qq];
    }
  }
  // wave-private LDS slab: no __syncthreads needed (same wave writes+reads).

  float* wsout = part + ((size_t)bid * 4 + h) * 36;
  if (lane < 34) {
    float t0 = 0.f;
#pragma unroll
    for (int l = 0; l < 16; ++l) t0 += lpart[h][l][lane];
    wsout[lane] = t0;
  }
}

// Combine partials -> normalize -> projection. FINAL adds dwconv residual +
// final linear. grid = 324 tiles, block = 256 (wave = query).
template <bool FINAL>
__global__ __launch_bounds__(256) void nat_combine(
    const float* __restrict__ part, const float* __restrict__ pw,
    const float* __restrict__ pb, const float* __restrict__ x,
    const float* __restrict__ dww, const float* __restrict__ dwb,
    const float* __restrict__ lw, const float* __restrict__ lb,
    float* __restrict__ out) {
  __shared__ float att[4][64];
  __shared__ float y_lds[4][64];
  const int tid = threadIdx.x;
  const int q = tid >> 6, lane = tid & 63;
  const int tile = blockIdx.x;
  const int i0 = (tile / 18) * 2, j0 = (tile % 18) * 2;
  const int p = q >> 1, qq = q & 1;
  const int iq = i0 + p, jq = j0 + qq;
  const int n = iq * 36 + jq;

  const int hh = lane >> 4, dd = lane & 15;
  // record for (tile, s, p, hh): ((tile*8 + s*2 + p)*4 + hh) * 36
  const float* pbase = part + ((size_t)tile * 8 + p) * 144 + hh * 36 + qq * 17;
  float num = 0.f, den = 0.f;
#pragma unroll
  for (int sp = 0; sp < 4; ++sp) {
    num += pbase[sp * 288 + dd];
    den += pbase[sp * 288 + 16];
  }
  att[q][lane] = num / den;
  __syncthreads();

  const float4* w4 = (const float4*)(pw + lane * 64);
  float a = pb[lane];
#pragma unroll
  for (int u = 0; u < 16; ++u) {
    float4 wv = w4[u];
    a += att[q][u * 4 + 0] * wv.x + att[q][u * 4 + 1] * wv.y +
         att[q][u * 4 + 2] * wv.z + att[q][u * 4 + 3] * wv.w;
  }

  if (!FINAL) {
    out[n * 64 + lane] = a;
  } else {
    float y = a + dwb[lane];
#pragma unroll
    for (int di = -1; di <= 1; ++di) {
#pragma unroll
      for (int dj = -1; dj <= 1; ++dj) {
        const int ii = iq + di, jj = jq + dj;
        if (ii >= 0 && ii < 36 && jj >= 0 && jj < 36)
          y += x[(ii * 36 + jj) * 64 + lane] * dww[lane * 9 + (di + 1) * 3 + (dj + 1)];
      }
    }
    y_lds[q][lane] = y;
    __syncthreads();
    const float4* l4 = (const float4*)(lw + lane * 64);
    float o = lb[lane];
#pragma unroll
    for (int u = 0; u < 16; ++u) {
      float4 wv = l4[u];
      o += y_lds[q][u * 4 + 0] * wv.x + y_lds[q][u * 4 + 1] * wv.y +
           y_lds[q][u * 4 + 2] * wv.z + y_lds[q][u * 4 + 3] * wv.w;
    }
    out[n * 64 + lane] = o;
  }
}

}  // namespace

extern "C" void kernel_launch(void* const* d_in, const int* in_sizes, int n_in,
                              void* d_out, int out_size, void* d_ws, size_t ws_size,
                              hipStream_t stream) {
  const float* x       = (const float*)d_in[0];
  const float* qkv_w1  = (const float*)d_in[3];
  const float* qkv_b1  = (const float*)d_in[4];
  const float* rpb1    = (const float*)d_in[5];
  const float* proj_w1 = (const float*)d_in[6];
  const float* proj_b1 = (const float*)d_in[7];
  const float* qkv_w2  = (const float*)d_in[8];
  const float* qkv_b2  = (const float*)d_in[9];
  const float* rpb2    = (const float*)d_in[10];
  const float* proj_w2 = (const float*)d_in[11];
  const float* proj_b2 = (const float*)d_in[12];
  const float* dw_w    = (const float*)d_in[13];
  const float* dw_b    = (const float*)d_in[14];
  const float* lin_w   = (const float*)d_in[15];
  const float* lin_b   = (const float*)d_in[16];
  float* out = (float*)d_out;

  float* ws = (float*)d_ws;
  float* qkvb  = ws;             // 1296*192  = 248832 floats
  float* natA  = ws + 248832;    // 1296*64   =  82944 floats
  float* partb = natA + 82944;   // 2592*4*36 = 373248 floats

  // layer 1
  qkv_gemm<<<972, 256, 0, stream>>>(x, qkv_w1, qkv_b1, qkvb);
  nat_attn_part<<<2592, 256, 0, stream>>>(qkvb, rpb1, partb);
  nat_combine<false><<<324, 256, 0, stream>>>(partb, proj_w1, proj_b1, nullptr,
                                              nullptr, nullptr, nullptr, nullptr,
                                              natA);
  // layer 2
  qkv_gemm<<<972, 256, 0, stream>>>(natA, qkv_w2, qkv_b2, qkvb);
  nat_attn_part<<<2592, 256, 0, stream>>>(qkvb, rpb2, partb);
  // layer-2 combine fused with dwconv residual + final linear
  nat_combine<true><<<324, 256, 0, stream>>>(partb, proj_w2, proj_b2, x,
                                             dw_w, dw_b, lin_w, lin_b, out);
}

// Round 6
// 208.465 us; speedup vs baseline: 1.6178x; 1.6178x over previous
//
#include <hip/hip_runtime.h>

// ConvNat: 2x NAT(31x31, 4 heads, dh=16) on 36x36x64 + dw-conv3x3 residual + linear.
// fp32. R5: R4 split-K structure with launch_bounds(256,2) — min-waves=4 made the
// backend squeeze to 64 VGPRs and spill ~40 regs/lane (114MB fetch + 216MB write
// of scratch traffic). (256,2) gives the allocator room: ~100 VGPR, no spill,
// HW still fits 5 waves/SIMD.

namespace {

__device__ __forceinline__ int iclampi(int v, int lo, int hi) {
  return v < lo ? lo : (v > hi ? hi : v);
}

// out[n][t] = b[t] + sum_c x[n][c] * w[t][c]
// grid = 972 (4 pixels x 64-out chunk per block), block = 256
__global__ __launch_bounds__(256) void qkv_gemm(const float* __restrict__ xin,
                                                const float* __restrict__ w,
                                                const float* __restrict__ b,
                                                float* __restrict__ out) {
  __shared__ float xs[4][64];
  const int blk = blockIdx.x;
  const int oc = blk % 3;
  const int p0 = (blk / 3) * 4;
  const int tid = threadIdx.x;
  const int pl = tid >> 6, co = tid & 63;
  const int n = p0 + pl;
  xs[pl][co] = xin[n * 64 + co];
  __syncthreads();
  const int t = oc * 64 + co;
  const float4* w4 = (const float4*)(w + t * 64);
  float acc = b[t];
#pragma unroll
  for (int u = 0; u < 16; ++u) {
    float4 wv = w4[u];
    acc += xs[pl][u * 4 + 0] * wv.x + xs[pl][u * 4 + 1] * wv.y +
           xs[pl][u * 4 + 2] * wv.z + xs[pl][u * 4 + 3] * wv.w;
  }
  out[n * 192 + t] = acc;
}

// Split-K NAT partials, 2 queries per lane.
// grid = 324*4*2: bid -> tile = bid>>3, s = (bid>>1)&3, pr = bid&1.
// Block's queries: (i0+pr, j0) and (i0+pr, j0+1). Wave = head.
// Split s covers key rows [s*8, s*8+8) of the tile's <=32-row window union.
// Output record per (bid, head): 36 floats  [qq*17+d]=acc, [qq*17+16]=den.
// launch_bounds(256,2): min-waves=4 forced a 64-VGPR budget -> ~40 regs/lane
// spilled -> 330MB scratch traffic (R3/R4). At (256,2) allocator uses ~100.
__global__ __launch_bounds__(256, 2) void nat_attn_part(
    const float* __restrict__ qkv, const float* __restrict__ rpb,
    float* __restrict__ part) {
  __shared__ float lpart[4][16][35];  // [head][group][2q*17] stride 35 (odd)

  const int tid = threadIdx.x;
  const int h = tid >> 6;
  const int lane = tid & 63;
  const int bid = blockIdx.x;
  const int tile = bid >> 3;
  const int s = (bid >> 1) & 3;
  const int pr = bid & 1;
  const int i0 = (tile / 18) * 2;
  const int j0 = (tile % 18) * 2;

  // union window over the parent 2x2 tile (<= 32x32)
  const int r_lo = iclampi(i0 - 15, 0, 5);
  const int nRr = (iclampi(i0 - 14, 0, 5) + 30) - r_lo;  // 30 or 31
  const int c_lo = iclampi(j0 - 15, 0, 5);
  const int nCc = (iclampi(j0 - 14, 0, 5) + 30) - c_lo;

  const int iq = i0 + pr;                       // shared row of both queries
  const int riq = iclampi(iq - 15, 0, 5);
  int jq[2], cjq[2];
#pragma unroll
  for (int qq = 0; qq < 2; ++qq) {
    jq[qq] = j0 + qq;
    cjq[qq] = iclampi(jq[qq] - 15, 0, 5);
  }

  // queries, pre-scaled by dh^-0.5 = 0.25 (broadcast loads)
  float qv[2][16];
#pragma unroll
  for (int qq = 0; qq < 2; ++qq) {
    const float4* qp = (const float4*)(qkv + (iq * 36 + jq[qq]) * 192 + h * 16);
#pragma unroll
    for (int u = 0; u < 4; ++u) {
      float4 q4 = qp[u];
      qv[qq][u * 4 + 0] = q4.x * 0.25f;
      qv[qq][u * 4 + 1] = q4.y * 0.25f;
      qv[qq][u * 4 + 2] = q4.z * 0.25f;
      qv[qq][u * 4 + 3] = q4.w * 0.25f;
    }
  }

  float acc[2][16];
  float sden[2] = {0.f, 0.f};
#pragma unroll
  for (int qq = 0; qq < 2; ++qq)
#pragma unroll
    for (int d = 0; d < 16; ++d) acc[qq][d] = 0.f;

  const int lr = lane >> 5;
  const int lc = lane & 31;

#pragma unroll
  for (int rp = 0; rp < 4; ++rp) {
    const int krr = s * 8 + rp * 2 + lr;
    const int rA = r_lo + krr;
    const int cA = c_lo + lc;
    const bool act = (krr <= nRr) && (lc <= nCc);
    const int rL = rA > 35 ? 35 : rA;
    const int cL = cA > 35 ? 35 : cA;
    const float* kbase = qkv + (rL * 36 + cL) * 192 + 64 + h * 16;
    float vr_[16];
    float dot[2] = {0.f, 0.f};
#pragma unroll
    for (int u = 0; u < 4; ++u) {
      float4 k4 = ((const float4*)kbase)[u];
      dot[0] += qv[0][u * 4 + 0] * k4.x + qv[0][u * 4 + 1] * k4.y +
                qv[0][u * 4 + 2] * k4.z + qv[0][u * 4 + 3] * k4.w;
      dot[1] += qv[1][u * 4 + 0] * k4.x + qv[1][u * 4 + 1] * k4.y +
                qv[1][u * 4 + 2] * k4.z + qv[1][u * 4 + 3] * k4.w;
      float4 v4 = ((const float4*)(kbase + 64))[u];
      vr_[u * 4 + 0] = v4.x; vr_[u * 4 + 1] = v4.y;
      vr_[u * 4 + 2] = v4.z; vr_[u * 4 + 3] = v4.w;
    }
    const bool rowok = act && (rA >= riq) && (rA <= riq + 30);
    const int br = iclampi(rA - iq + 30, 0, 60);
#pragma unroll
    for (int qq = 0; qq < 2; ++qq) {
      const bool inw = rowok && (cA >= cjq[qq]) && (cA <= cjq[qq] + 30);
      const int bc = iclampi(cA - jq[qq] + 30, 0, 60);
      const float bias = rpb[h * 3721 + br * 61 + bc];
      // |logits| << 1 for this input distribution; clamp = overflow insurance
      const float lg = fminf(dot[qq] + bias, 25.f);
      const float p = inw ? __expf(lg) : 0.f;
      sden[qq] += p;
#pragma unroll
      for (int d = 0; d < 16; ++d) acc[qq][d] += p * vr_[d];
    }
  }

  // 2-step butterfly -> 16 groups of 4 lanes
#pragma unroll
  for (int qq = 0; qq < 2; ++qq) {
#pragma unroll
    for (int d = 0; d < 16; ++d) {
      acc[qq][d] += __shfl_xor(acc[qq][d], 1);
      acc[qq][d] += __shfl_xor(acc[qq][d], 2);
    }
    sden[qq] += __shfl_xor(sden[qq], 1);
    sden[qq] += __shfl_xor(sden[qq], 2);
  }

  if ((lane & 3) == 0) {
    const int row = lane >> 2;
#pragma unroll
    for (int qq = 0; qq < 2; ++qq) {
#pragma unroll
      for (int d = 0; d < 16; ++d) lpart[h][row][qq * 17 + d] = acc[qq][d];
      lpart[h][row][qq * 17 + 16] = sden[qq];
    }
  }
  // wave-private LDS slab: no __syncthreads needed (same wave writes+reads).

  float* wsout = part + ((size_t)bid * 4 + h) * 36;
  if (lane < 34) {
    float t0 = 0.f;
#pragma unroll
    for (int l = 0; l < 16; ++l) t0 += lpart[h][l][lane];
    wsout[lane] = t0;
  }
}

// Combine partials -> normalize -> projection. FINAL adds dwconv residual +
// final linear. grid = 324 tiles, block = 256 (wave = query).
template <bool FINAL>
__global__ __launch_bounds__(256) void nat_combine(
    const float* __restrict__ part, const float* __restrict__ pw,
    const float* __restrict__ pb, const float* __restrict__ x,
    const float* __restrict__ dww, const float* __restrict__ dwb,
    const float* __restrict__ lw, const float* __restrict__ lb,
    float* __restrict__ out) {
  __shared__ float att[4][64];
  __shared__ float y_lds[4][64];
  const int tid = threadIdx.x;
  const int q = tid >> 6, lane = tid & 63;
  const int tile = blockIdx.x;
  const int i0 = (tile / 18) * 2, j0 = (tile % 18) * 2;
  const int p = q >> 1, qq = q & 1;
  const int iq = i0 + p, jq = j0 + qq;
  const int n = iq * 36 + jq;

  const int hh = lane >> 4, dd = lane & 15;
  // record for (tile, s, p, hh): ((tile*8 + s*2 + p)*4 + hh) * 36
  const float* pbase = part + ((size_t)tile * 8 + p) * 144 + hh * 36 + qq * 17;
  float num = 0.f, den = 0.f;
#pragma unroll
  for (int sp = 0; sp < 4; ++sp) {
    num += pbase[sp * 288 + dd];
    den += pbase[sp * 288 + 16];
  }
  att[q][lane] = num / den;
  __syncthreads();

  const float4* w4 = (const float4*)(pw + lane * 64);
  float a = pb[lane];
#pragma unroll
  for (int u = 0; u < 16; ++u) {
    float4 wv = w4[u];
    a += att[q][u * 4 + 0] * wv.x + att[q][u * 4 + 1] * wv.y +
         att[q][u * 4 + 2] * wv.z + att[q][u * 4 + 3] * wv.w;
  }

  if (!FINAL) {
    out[n * 64 + lane] = a;
  } else {
    float y = a + dwb[lane];
#pragma unroll
    for (int di = -1; di <= 1; ++di) {
#pragma unroll
      for (int dj = -1; dj <= 1; ++dj) {
        const int ii = iq + di, jj = jq + dj;
        if (ii >= 0 && ii < 36 && jj >= 0 && jj < 36)
          y += x[(ii * 36 + jj) * 64 + lane] * dww[lane * 9 + (di + 1) * 3 + (dj + 1)];
      }
    }
    y_lds[q][lane] = y;
    __syncthreads();
    const float4* l4 = (const float4*)(lw + lane * 64);
    float o = lb[lane];
#pragma unroll
    for (int u = 0; u < 16; ++u) {
      float4 wv = l4[u];
      o += y_lds[q][u * 4 + 0] * wv.x + y_lds[q][u * 4 + 1] * wv.y +
           y_lds[q][u * 4 + 2] * wv.z + y_lds[q][u * 4 + 3] * wv.w;
    }
    out[n * 64 + lane] = o;
  }
}

}  // namespace

extern "C" void kernel_launch(void* const* d_in, const int* in_sizes, int n_in,
                              void* d_out, int out_size, void* d_ws, size_t ws_size,
                              hipStream_t stream) {
  const float* x       = (const float*)d_in[0];
  const float* qkv_w1  = (const float*)d_in[3];
  const float* qkv_b1  = (const float*)d_in[4];
  const float* rpb1    = (const float*)d_in[5];
  const float* proj_w1 = (const float*)d_in[6];
  const float* proj_b1 = (const float*)d_in[7];
  const float* qkv_w2  = (const float*)d_in[8];
  const float* qkv_b2  = (const float*)d_in[9];
  const float* rpb2    = (const float*)d_in[10];
  const float* proj_w2 = (const float*)d_in[11];
  const float* proj_b2 = (const float*)d_in[12];
  const float* dw_w    = (const float*)d_in[13];
  const float* dw_b    = (const float*)d_in[14];
  const float* lin_w   = (const float*)d_in[15];
  const float* lin_b   = (const float*)d_in[16];
  float* out = (float*)d_out;

  float* ws = (float*)d_ws;
  float* qkvb  = ws;             // 1296*192  = 248832 floats
  float* natA  = ws + 248832;    // 1296*64   =  82944 floats
  float* partb = natA + 82944;   // 2592*4*36 = 373248 floats

  // layer 1
  qkv_gemm<<<972, 256, 0, stream>>>(x, qkv_w1, qkv_b1, qkvb);
  nat_attn_part<<<2592, 256, 0, stream>>>(qkvb, rpb1, partb);
  nat_combine<false><<<324, 256, 0, stream>>>(partb, proj_w1, proj_b1, nullptr,
                                              nullptr, nullptr, nullptr, nullptr,
                                              natA);
  // layer 2
  qkv_gemm<<<972, 256, 0, stream>>>(natA, qkv_w2, qkv_b2, qkvb);
  nat_attn_part<<<2592, 256, 0, stream>>>(qkvb, rpb2, partb);
  // layer-2 combine fused with dwconv residual + final linear
  nat_combine<true><<<324, 256, 0, stream>>>(partb, proj_w2, proj_b2, x,
                                             dw_w, dw_b, lin_w, lin_b, out);
}

// Round 10
// 205.920 us; speedup vs baseline: 1.6378x; 1.0124x over previous
//
#include <hip/hip_runtime.h>

// ConvNat: 2x NAT(31x31, 4 heads, dh=16) on 36x36x64 + dw-conv3x3 residual + linear.
// fp32. R7: planar (SoA) Q/K/V layout [row=h*16+d][pixel] so attention K/V loads
// are lane-coalesced (4 lines/instr instead of 64 — R6 was L1-transaction-bound).
// Register-blocked qkv GEMM (x in VGPRs, scalar w loads). Pre-transposed proj/lin
// weights for coalesced combine loads.

namespace {

__device__ __forceinline__ int iclampi(int v, int lo, int hi) {
  return v < lo ? lo : (v > hi ? hi : v);
}

// Transpose three 64x64 matrices (proj_w1, proj_w2, lin_w) -> outT[m][c][t].
// grid = 48 (16 blocks per matrix), block = 256.
__global__ __launch_bounds__(256) void transpose_w(
    const float* __restrict__ a, const float* __restrict__ b2,
    const float* __restrict__ c, float* __restrict__ outT) {
  const int m = blockIdx.x >> 4;
  const int idx = (blockIdx.x & 15) * 256 + threadIdx.x;
  const float* src = m == 0 ? a : (m == 1 ? b2 : c);
  const int t = idx >> 6, cc = idx & 63;
  outT[m * 4096 + cc * 64 + t] = src[idx];
}

// planes[r][n] = b[r] + sum_c x[n][c] * w[r][c]   (r in [0,192), n in [0,1296))
// grid = (21, 2), block = 256. lane = pixel; wave computes 24 rows for 64 pixels.
// x row held in 64 VGPRs; w rows read via scalar (readfirstlane) loads.
__global__ __launch_bounds__(256) void qkv_gemm_planar(
    const float* __restrict__ xin, const float* __restrict__ w,
    const float* __restrict__ b, float* __restrict__ planes) {
  const int tid = threadIdx.x;
  const int wv = tid >> 6, lane = tid & 63;
  const int n = blockIdx.x * 64 + lane;
  const int nL = n < 1295 ? n : 1295;
  float xr[64];
  const float4* xp = (const float4*)(xin + nL * 64);
#pragma unroll
  for (int u = 0; u < 16; ++u) {
    float4 v = xp[u];
    xr[u * 4 + 0] = v.x; xr[u * 4 + 1] = v.y;
    xr[u * 4 + 2] = v.z; xr[u * 4 + 3] = v.w;
  }
  const int r0 = blockIdx.y * 96 + wv * 24;
  for (int r = 0; r < 24; ++r) {
    const int rr = __builtin_amdgcn_readfirstlane(r0 + r);  // force SGPR addr
    const float* wr = w + rr * 64;
    float acc = b[rr];
#pragma unroll
    for (int cc = 0; cc < 64; ++cc) acc += wr[cc] * xr[cc];
    if (n < 1296) planes[rr * 1296 + n] = acc;
  }
}

// Split-K NAT partials on planar K/V. grid = 324*4*2 as in R5/R6; wave = head.
// K/V loads: K[d*1296 + nk], lanes = consecutive window cols -> coalesced.
__global__ __launch_bounds__(256, 2) void nat_attn_part(
    const float* __restrict__ planes, const float* __restrict__ rpb,
    float* __restrict__ part) {
  __shared__ float lpart[4][16][35];  // [head][group][2q*17] stride 35 (odd)

  const int tid = threadIdx.x;
  const int h = tid >> 6;
  const int lane = tid & 63;
  const int bid = blockIdx.x;
  const int tile = bid >> 3;
  const int s = (bid >> 1) & 3;
  const int pr = bid & 1;
  const int i0 = (tile / 18) * 2;
  const int j0 = (tile % 18) * 2;

  const int r_lo = iclampi(i0 - 15, 0, 5);
  const int nRr = (iclampi(i0 - 14, 0, 5) + 30) - r_lo;  // 30 or 31
  const int c_lo = iclampi(j0 - 15, 0, 5);
  const int nCc = (iclampi(j0 - 14, 0, 5) + 30) - c_lo;

  const int iq = i0 + pr;
  const int riq = iclampi(iq - 15, 0, 5);
  int jq[2], cjq[2];
#pragma unroll
  for (int qq = 0; qq < 2; ++qq) {
    jq[qq] = j0 + qq;
    cjq[qq] = iclampi(jq[qq] - 15, 0, 5);
  }

  const float* Qp = planes + (size_t)(h * 16) * 1296;
  const float* Kp = planes + (size_t)(64 + h * 16) * 1296;
  const float* Vp = planes + (size_t)(128 + h * 16) * 1296;

  // queries (broadcast loads), pre-scaled by dh^-0.5 = 0.25
  float qv[2][16];
#pragma unroll
  for (int qq = 0; qq < 2; ++qq) {
    const int nq = iq * 36 + jq[qq];
#pragma unroll
    for (int d = 0; d < 16; ++d) qv[qq][d] = Qp[d * 1296 + nq] * 0.25f;
  }

  float acc[2][16];
  float sden[2] = {0.f, 0.f};
#pragma unroll
  for (int qq = 0; qq < 2; ++qq)
#pragma unroll
    for (int d = 0; d < 16; ++d) acc[qq][d] = 0.f;

  const int lr = lane >> 5;
  const int lc = lane & 31;

#pragma unroll
  for (int rp = 0; rp < 4; ++rp) {
    const int krr = s * 8 + rp * 2 + lr;
    const int rA = r_lo + krr;
    const int cA = c_lo + lc;
    const bool act = (krr <= nRr) && (lc <= nCc);
    const int rL = rA > 35 ? 35 : rA;
    const int cL = cA > 35 ? 35 : cA;
    const int nk = rL * 36 + cL;
    float kr_[16], vr_[16];
#pragma unroll
    for (int d = 0; d < 16; ++d) kr_[d] = Kp[d * 1296 + nk];
#pragma unroll
    for (int d = 0; d < 16; ++d) vr_[d] = Vp[d * 1296 + nk];

    float dot[2] = {0.f, 0.f};
#pragma unroll
    for (int d = 0; d < 16; ++d) {
      dot[0] += qv[0][d] * kr_[d];
      dot[1] += qv[1][d] * kr_[d];
    }
    const bool rowok = act && (rA >= riq) && (rA <= riq + 30);
    const int br = iclampi(rA - iq + 30, 0, 60);
#pragma unroll
    for (int qq = 0; qq < 2; ++qq) {
      const bool inw = rowok && (cA >= cjq[qq]) && (cA <= cjq[qq] + 30);
      const int bc = iclampi(cA - jq[qq] + 30, 0, 60);
      const float bias = rpb[h * 3721 + br * 61 + bc];
      const float lg = fminf(dot[qq] + bias, 25.f);  // overflow insurance
      const float p = inw ? __expf(lg) : 0.f;
      sden[qq] += p;
#pragma unroll
      for (int d = 0; d < 16; ++d) acc[qq][d] += p * vr_[d];
    }
  }

  // 2-step butterfly -> 16 groups of 4 lanes
#pragma unroll
  for (int qq = 0; qq < 2; ++qq) {
#pragma unroll
    for (int d = 0; d < 16; ++d) {
      acc[qq][d] += __shfl_xor(acc[qq][d], 1);
      acc[qq][d] += __shfl_xor(acc[qq][d], 2);
    }
    sden[qq] += __shfl_xor(sden[qq], 1);
    sden[qq] += __shfl_xor(sden[qq], 2);
  }

  if ((lane & 3) == 0) {
    const int row = lane >> 2;
#pragma unroll
    for (int qq = 0; qq < 2; ++qq) {
#pragma unroll
      for (int d = 0; d < 16; ++d) lpart[h][row][qq * 17 + d] = acc[qq][d];
      lpart[h][row][qq * 17 + 16] = sden[qq];
    }
  }
  // wave-private LDS slab: same wave writes+reads, no __syncthreads needed.

  float* wsout = part + ((size_t)bid * 4 + h) * 36;
  if (lane < 34) {
    float t0 = 0.f;
#pragma unroll
    for (int l = 0; l < 16; ++l) t0 += lpart[h][l][lane];
    wsout[lane] = t0;
  }
}

// Combine partials -> normalize -> projection (transposed weights, coalesced).
// FINAL adds dwconv residual + final linear. grid = 324, block = 256 (wave=query).
template <bool FINAL>
__global__ __launch_bounds__(256) void nat_combine(
    const float* __restrict__ part, const float* __restrict__ pwT,
    const float* __restrict__ pb, const float* __restrict__ x,
    const float* __restrict__ dww, const float* __restrict__ dwb,
    const float* __restrict__ linT, const float* __restrict__ lb,
    float* __restrict__ out) {
  __shared__ float att[4][64];
  __shared__ float y_lds[4][64];
  const int tid = threadIdx.x;
  const int q = tid >> 6, lane = tid & 63;
  const int tile = blockIdx.x;
  const int i0 = (tile / 18) * 2, j0 = (tile % 18) * 2;
  const int p = q >> 1, qq = q & 1;
  const int iq = i0 + p, jq = j0 + qq;
  const int n = iq * 36 + jq;

  const int hh = lane >> 4, dd = lane & 15;
  // record for (tile, s, p, hh): ((tile*8 + s*2 + p)*4 + hh) * 36
  const float* pbase = part + ((size_t)tile * 8 + p) * 144 + hh * 36 + qq * 17;
  float num = 0.f, den = 0.f;
#pragma unroll
  for (int sp = 0; sp < 4; ++sp) {
    num += pbase[sp * 288 + dd];
    den += pbase[sp * 288 + 16];
  }
  att[q][lane] = num / den;
  __syncthreads();

  float a = pb[lane];
#pragma unroll
  for (int cc = 0; cc < 64; ++cc) a += att[q][cc] * pwT[cc * 64 + lane];

  if (!FINAL) {
    out[n * 64 + lane] = a;
  } else {
    float y = a + dwb[lane];
#pragma unroll
    for (int di = -1; di <= 1; ++di) {
#pragma unroll
      for (int dj = -1; dj <= 1; ++dj) {
        const int ii = iq + di, jj = jq + dj;
        if (ii >= 0 && ii < 36 && jj >= 0 && jj < 36)
          y += x[(ii * 36 + jj) * 64 + lane] * dww[lane * 9 + (di + 1) * 3 + (dj + 1)];
      }
    }
    y_lds[q][lane] = y;
    __syncthreads();
    float o = lb[lane];
#pragma unroll
    for (int cc = 0; cc < 64; ++cc) o += y_lds[q][cc] * linT[cc * 64 + lane];
    out[n * 64 + lane] = o;
  }
}

}  // namespace

extern "C" void kernel_launch(void* const* d_in, const int* in_sizes, int n_in,
                              void* d_out, int out_size, void* d_ws, size_t ws_size,
                              hipStream_t stream) {
  const float* x       = (const float*)d_in[0];
  const float* qkv_w1  = (const float*)d_in[3];
  const float* qkv_b1  = (const float*)d_in[4];
  const float* rpb1    = (const float*)d_in[5];
  const float* proj_w1 = (const float*)d_in[6];
  const float* proj_b1 = (const float*)d_in[7];
  const float* qkv_w2  = (const float*)d_in[8];
  const float* qkv_b2  = (const float*)d_in[9];
  const float* rpb2    = (const float*)d_in[10];
  const float* proj_w2 = (const float*)d_in[11];
  const float* proj_b2 = (const float*)d_in[12];
  const float* dw_w    = (const float*)d_in[13];
  const float* dw_b    = (const float*)d_in[14];
  const float* lin_w   = (const float*)d_in[15];
  const float* lin_b   = (const float*)d_in[16];
  float* out = (float*)d_out;

  float* ws = (float*)d_ws;
  float* planes = ws;              // 192*1296  = 248832 floats
  float* natA   = ws + 248832;     // 1296*64   =  82944 floats
  float* partb  = natA + 82944;    // 2592*4*36 = 373248 floats
  float* wT     = partb + 373248;  // 3*4096    =  12288 floats
  float* pwT1 = wT;
  float* pwT2 = wT + 4096;
  float* linT = wT + 8192;

  // pre-transpose proj/lin weights (once per call)
  transpose_w<<<48, 256, 0, stream>>>(proj_w1, proj_w2, lin_w, wT);

  dim3 ggrid(21, 2);
  // layer 1
  qkv_gemm_planar<<<ggrid, 256, 0, stream>>>(x, qkv_w1, qkv_b1, planes);
  nat_attn_part<<<2592, 256, 0, stream>>>(planes, rpb1, partb);
  nat_combine<false><<<324, 256, 0, stream>>>(partb, pwT1, proj_b1, nullptr,
                                              nullptr, nullptr, nullptr, nullptr,
                                              natA);
  // layer 2
  qkv_gemm_planar<<<ggrid, 256, 0, stream>>>(natA, qkv_w2, qkv_b2, planes);
  nat_attn_part<<<2592, 256, 0, stream>>>(planes, rpb2, partb);
  // layer-2 combine fused with dwconv residual + final linear
  nat_combine<true><<<324, 256, 0, stream>>>(partb, pwT2, proj_b2, x,
                                             dw_w, dw_b, linT, lin_b, out);
}

// Round 11
// 166.579 us; speedup vs baseline: 2.0246x; 1.2362x over previous
//
#include <hip/hip_runtime.h>

// ConvNat: 2x NAT(31x31, 4 heads, dh=16) on 36x36x64 + dw-conv3x3 residual + linear.
// fp32. R11: R7 planar pipeline, but qkv GEMM rebuilt for occupancy — R10's
// 42-block/serial-row version was ~38us/launch (hidden below the 40us harness
// fills in top-5). Now 1008 blocks: LDS x-tile [64][65], wave = one qkv row x 64
// pixels, coalesced planar writes. Weight-transpose merged into qkv layer-1 grid.

namespace {

__device__ __forceinline__ int iclampi(int v, int lo, int hi) {
  return v < lo ? lo : (v > hi ? hi : v);
}

// Fused qkv GEMM (planar out) + (layer 1 only) proj/lin weight transposes.
// qkv blocks [0,1008): bid -> pg = bid%21 (64-pixel group), rg = bid/21 (4-row
// group of the 192 qkv rows). 4 waves; wave wv computes row rg*4+wv for the
// group's 64 pixels: planes[r][n] = b[r] + sum_c in[n][c]*w[r][c].
// x tile staged in LDS [64][65] (pad -> 2-way bank alias, free per m136);
// w rows staged in LDS (wave-broadcast reads). Writes coalesced over n.
// WITH_T blocks [1008,1056): transpose proj_w1/proj_w2/lin_w into wT.
template <bool WITH_T>
__global__ __launch_bounds__(256) void qkv_fused(
    const float* __restrict__ xin, const float* __restrict__ w,
    const float* __restrict__ b, float* __restrict__ planes,
    const float* __restrict__ pw1, const float* __restrict__ pw2,
    const float* __restrict__ lw, float* __restrict__ wT) {
  const int bid = blockIdx.x;
  const int tid = threadIdx.x;
  if (WITH_T && bid >= 1008) {
    const int t = bid - 1008;  // 0..47, 16 blocks per 64x64 matrix
    const int m = t >> 4;
    const int idx = (t & 15) * 256 + tid;
    const float* src = m == 0 ? pw1 : (m == 1 ? pw2 : lw);
    wT[m * 4096 + (idx & 63) * 64 + (idx >> 6)] = src[idx];
    return;
  }
  __shared__ float xs[64][65];
  __shared__ float ws4[4][64];
  const int pg = bid % 21, rg = bid / 21;
  const int wv = tid >> 6, lane = tid & 63;
  const int n0 = pg * 64;
  const int base = n0 * 64;
  const int maxf = 82944 - base;  // valid floats in this 64-pixel window
  const float* xb = xin + base;
#pragma unroll
  for (int t4 = 0; t4 < 4; ++t4) {
    const int fi = (tid + t4 * 256) * 4;
    float4 v = make_float4(0.f, 0.f, 0.f, 0.f);
    if (fi < maxf) v = *(const float4*)(xb + fi);  // maxf % 64 == 0 -> safe
    const int p = fi >> 6, c = fi & 63;
    xs[p][c] = v.x; xs[p][c + 1] = v.y; xs[p][c + 2] = v.z; xs[p][c + 3] = v.w;
  }
  ws4[tid >> 6][tid & 63] = w[rg * 256 + tid];  // 4 rows, coalesced
  __syncthreads();
  const int r = rg * 4 + wv;
  float acc = b[r];
#pragma unroll
  for (int cc = 0; cc < 64; ++cc) acc += xs[lane][cc] * ws4[wv][cc];
  const int n = n0 + lane;
  if (n < 1296) planes[r * 1296 + n] = acc;
}

// Split-K NAT partials on planar K/V. grid = 324*4*2; wave = head.
// K/V loads: K[d*1296 + nk], lanes = consecutive window cols -> coalesced.
__global__ __launch_bounds__(256, 2) void nat_attn_part(
    const float* __restrict__ planes, const float* __restrict__ rpb,
    float* __restrict__ part) {
  __shared__ float lpart[4][16][35];  // [head][group][2q*17] stride 35 (odd)

  const int tid = threadIdx.x;
  const int h = tid >> 6;
  const int lane = tid & 63;
  const int bid = blockIdx.x;
  const int tile = bid >> 3;
  const int s = (bid >> 1) & 3;
  const int pr = bid & 1;
  const int i0 = (tile / 18) * 2;
  const int j0 = (tile % 18) * 2;

  const int r_lo = iclampi(i0 - 15, 0, 5);
  const int nRr = (iclampi(i0 - 14, 0, 5) + 30) - r_lo;  // 30 or 31
  const int c_lo = iclampi(j0 - 15, 0, 5);
  const int nCc = (iclampi(j0 - 14, 0, 5) + 30) - c_lo;

  const int iq = i0 + pr;
  const int riq = iclampi(iq - 15, 0, 5);
  int jq[2], cjq[2];
#pragma unroll
  for (int qq = 0; qq < 2; ++qq) {
    jq[qq] = j0 + qq;
    cjq[qq] = iclampi(jq[qq] - 15, 0, 5);
  }

  const float* Qp = planes + (size_t)(h * 16) * 1296;
  const float* Kp = planes + (size_t)(64 + h * 16) * 1296;
  const float* Vp = planes + (size_t)(128 + h * 16) * 1296;

  // queries (broadcast loads), pre-scaled by dh^-0.5 = 0.25
  float qv[2][16];
#pragma unroll
  for (int qq = 0; qq < 2; ++qq) {
    const int nq = iq * 36 + jq[qq];
#pragma unroll
    for (int d = 0; d < 16; ++d) qv[qq][d] = Qp[d * 1296 + nq] * 0.25f;
  }

  float acc[2][16];
  float sden[2] = {0.f, 0.f};
#pragma unroll
  for (int qq = 0; qq < 2; ++qq)
#pragma unroll
    for (int d = 0; d < 16; ++d) acc[qq][d] = 0.f;

  const int lr = lane >> 5;
  const int lc = lane & 31;

#pragma unroll
  for (int rp = 0; rp < 4; ++rp) {
    const int krr = s * 8 + rp * 2 + lr;
    const int rA = r_lo + krr;
    const int cA = c_lo + lc;
    const bool act = (krr <= nRr) && (lc <= nCc);
    const int rL = rA > 35 ? 35 : rA;
    const int cL = cA > 35 ? 35 : cA;
    const int nk = rL * 36 + cL;
    float kr_[16], vr_[16];
#pragma unroll
    for (int d = 0; d < 16; ++d) kr_[d] = Kp[d * 1296 + nk];
#pragma unroll
    for (int d = 0; d < 16; ++d) vr_[d] = Vp[d * 1296 + nk];

    float dot[2] = {0.f, 0.f};
#pragma unroll
    for (int d = 0; d < 16; ++d) {
      dot[0] += qv[0][d] * kr_[d];
      dot[1] += qv[1][d] * kr_[d];
    }
    const bool rowok = act && (rA >= riq) && (rA <= riq + 30);
    const int br = iclampi(rA - iq + 30, 0, 60);
#pragma unroll
    for (int qq = 0; qq < 2; ++qq) {
      const bool inw = rowok && (cA >= cjq[qq]) && (cA <= cjq[qq] + 30);
      const int bc = iclampi(cA - jq[qq] + 30, 0, 60);
      const float bias = rpb[h * 3721 + br * 61 + bc];
      const float lg = fminf(dot[qq] + bias, 25.f);  // overflow insurance
      const float p = inw ? __expf(lg) : 0.f;
      sden[qq] += p;
#pragma unroll
      for (int d = 0; d < 16; ++d) acc[qq][d] += p * vr_[d];
    }
  }

  // 2-step butterfly -> 16 groups of 4 lanes
#pragma unroll
  for (int qq = 0; qq < 2; ++qq) {
#pragma unroll
    for (int d = 0; d < 16; ++d) {
      acc[qq][d] += __shfl_xor(acc[qq][d], 1);
      acc[qq][d] += __shfl_xor(acc[qq][d], 2);
    }
    sden[qq] += __shfl_xor(sden[qq], 1);
    sden[qq] += __shfl_xor(sden[qq], 2);
  }

  if ((lane & 3) == 0) {
    const int row = lane >> 2;
#pragma unroll
    for (int qq = 0; qq < 2; ++qq) {
#pragma unroll
      for (int d = 0; d < 16; ++d) lpart[h][row][qq * 17 + d] = acc[qq][d];
      lpart[h][row][qq * 17 + 16] = sden[qq];
    }
  }
  // wave-private LDS slab: same wave writes+reads, no __syncthreads needed.

  float* wsout = part + ((size_t)bid * 4 + h) * 36;
  if (lane < 34) {
    float t0 = 0.f;
#pragma unroll
    for (int l = 0; l < 16; ++l) t0 += lpart[h][l][lane];
    wsout[lane] = t0;
  }
}

// Combine partials -> normalize -> projection (transposed weights, coalesced).
// FINAL adds dwconv residual + final linear. grid = 324, block = 256 (wave=query).
template <bool FINAL>
__global__ __launch_bounds__(256) void nat_combine(
    const float* __restrict__ part, const float* __restrict__ pwT,
    const float* __restrict__ pb, const float* __restrict__ x,
    const float* __restrict__ dww, const float* __restrict__ dwb,
    const float* __restrict__ linT, const float* __restrict__ lb,
    float* __restrict__ out) {
  __shared__ float att[4][64];
  __shared__ float y_lds[4][64];
  const int tid = threadIdx.x;
  const int q = tid >> 6, lane = tid & 63;
  const int tile = blockIdx.x;
  const int i0 = (tile / 18) * 2, j0 = (tile % 18) * 2;
  const int p = q >> 1, qq = q & 1;
  const int iq = i0 + p, jq = j0 + qq;
  const int n = iq * 36 + jq;

  const int hh = lane >> 4, dd = lane & 15;
  // record for (tile, s, p, hh): ((tile*8 + s*2 + p)*4 + hh) * 36
  const float* pbase = part + ((size_t)tile * 8 + p) * 144 + hh * 36 + qq * 17;
  float num = 0.f, den = 0.f;
#pragma unroll
  for (int sp = 0; sp < 4; ++sp) {
    num += pbase[sp * 288 + dd];
    den += pbase[sp * 288 + 16];
  }
  att[q][lane] = num / den;
  __syncthreads();

  float a = pb[lane];
#pragma unroll
  for (int cc = 0; cc < 64; ++cc) a += att[q][cc] * pwT[cc * 64 + lane];

  if (!FINAL) {
    out[n * 64 + lane] = a;
  } else {
    float y = a + dwb[lane];
#pragma unroll
    for (int di = -1; di <= 1; ++di) {
#pragma unroll
      for (int dj = -1; dj <= 1; ++dj) {
        const int ii = iq + di, jj = jq + dj;
        if (ii >= 0 && ii < 36 && jj >= 0 && jj < 36)
          y += x[(ii * 36 + jj) * 64 + lane] * dww[lane * 9 + (di + 1) * 3 + (dj + 1)];
      }
    }
    y_lds[q][lane] = y;
    __syncthreads();
    float o = lb[lane];
#pragma unroll
    for (int cc = 0; cc < 64; ++cc) o += y_lds[q][cc] * linT[cc * 64 + lane];
    out[n * 64 + lane] = o;
  }
}

}  // namespace

extern "C" void kernel_launch(void* const* d_in, const int* in_sizes, int n_in,
                              void* d_out, int out_size, void* d_ws, size_t ws_size,
                              hipStream_t stream) {
  const float* x       = (const float*)d_in[0];
  const float* qkv_w1  = (const float*)d_in[3];
  const float* qkv_b1  = (const float*)d_in[4];
  const float* rpb1    = (const float*)d_in[5];
  const float* proj_w1 = (const float*)d_in[6];
  const float* proj_b1 = (const float*)d_in[7];
  const float* qkv_w2  = (const float*)d_in[8];
  const float* qkv_b2  = (const float*)d_in[9];
  const float* rpb2    = (const float*)d_in[10];
  const float* proj_w2 = (const float*)d_in[11];
  const float* proj_b2 = (const float*)d_in[12];
  const float* dw_w    = (const float*)d_in[13];
  const float* dw_b    = (const float*)d_in[14];
  const float* lin_w   = (const float*)d_in[15];
  const float* lin_b   = (const float*)d_in[16];
  float* out = (float*)d_out;

  float* ws = (float*)d_ws;
  float* planes = ws;              // 192*1296  = 248832 floats
  float* natA   = ws + 248832;     // 1296*64   =  82944 floats
  float* partb  = natA + 82944;    // 2592*4*36 = 373248 floats
  float* wT     = partb + 373248;  // 3*4096    =  12288 floats
  float* pwT1 = wT;
  float* pwT2 = wT + 4096;
  float* linT = wT + 8192;

  // layer 1 (qkv + weight transposes fused into one launch)
  qkv_fused<true><<<1056, 256, 0, stream>>>(x, qkv_w1, qkv_b1, planes,
                                            proj_w1, proj_w2, lin_w, wT);
  nat_attn_part<<<2592, 256, 0, stream>>>(planes, rpb1, partb);
  nat_combine<false><<<324, 256, 0, stream>>>(partb, pwT1, proj_b1, nullptr,
                                              nullptr, nullptr, nullptr, nullptr,
                                              natA);
  // layer 2
  qkv_fused<false><<<1008, 256, 0, stream>>>(natA, qkv_w2, qkv_b2, planes,
                                             nullptr, nullptr, nullptr, nullptr);
  nat_attn_part<<<2592, 256, 0, stream>>>(planes, rpb2, partb);
  // layer-2 combine fused with dwconv residual + final linear
  nat_combine<true><<<324, 256, 0, stream>>>(partb, pwT2, proj_b2, x,
                                             dw_w, dw_b, linT, lin_b, out);
}